// Round 5
// baseline (301.228 us; speedup 1.0000x reference)
//
#include <hip/hip_runtime.h>

#define Bdim 32
#define Tdim 256
#define Cdim 1024
#define Mrows (Bdim * Tdim) /* 8192 */

typedef unsigned short u16;
typedef unsigned int u32;
typedef __bf16 bf16x8 __attribute__((ext_vector_type(8)));
typedef float f32x4 __attribute__((ext_vector_type(4)));

__device__ __forceinline__ float bf2f(u32 u) {
    union { u32 i; float f; } v; v.i = u << 16; return v.f;
}
__device__ __forceinline__ u16 f2bf(float f) {
    union { float f; u32 i; } v; v.f = f;
    u32 u = v.i;
    return (u16)((u + 0x7fffu + ((u >> 16) & 1u)) >> 16);  // RNE
}

__device__ __forceinline__ void gload16(const u16* g, u16* l) {
    __builtin_amdgcn_global_load_lds(
        (__attribute__((address_space(1))) const void*)g,
        (__attribute__((address_space(3))) void*)l, 16, 0, 0);
}

// ---- fused prep (x mixing -> bf16) + weight convert ---------------------------
__global__ __launch_bounds__(256) void prep_fused(
    const float* __restrict__ x, const float* __restrict__ tmk,
    const float* __restrict__ tmv, const float* __restrict__ tmr,
    u16* __restrict__ xk, u16* __restrict__ xv, u16* __restrict__ xr,
    const float* __restrict__ w0, const float* __restrict__ w1,
    const float* __restrict__ w2, const float* __restrict__ w3,
    u16* __restrict__ o0, u16* __restrict__ o1,
    u16* __restrict__ o2, u16* __restrict__ o3)
{
    int bid = blockIdx.x;
    if (bid < 4096) {
        int tid = bid * 256 + threadIdx.x;
        int e = tid << 3;
        int c = e & (Cdim - 1);
        int t = (e >> 10) & (Tdim - 1);
        float xf[8], xxf[8], mk[8], mv[8], mr[8];
        *(float4*)(xf)     = *(const float4*)(x + e);
        *(float4*)(xf + 4) = *(const float4*)(x + e + 4);
        if (t != 0) {
            *(float4*)(xxf)     = *(const float4*)(x + e - Cdim);
            *(float4*)(xxf + 4) = *(const float4*)(x + e - Cdim + 4);
        } else {
#pragma unroll
            for (int j = 0; j < 8; j++) xxf[j] = 0.f;
        }
        *(float4*)(mk)     = *(const float4*)(tmk + c);
        *(float4*)(mk + 4) = *(const float4*)(tmk + c + 4);
        *(float4*)(mv)     = *(const float4*)(tmv + c);
        *(float4*)(mv + 4) = *(const float4*)(tmv + c + 4);
        *(float4*)(mr)     = *(const float4*)(tmr + c);
        *(float4*)(mr + 4) = *(const float4*)(tmr + c + 4);
        u16 ok[8], ov[8], orr[8];
#pragma unroll
        for (int j = 0; j < 8; j++) {
            float d = xf[j] - xxf[j];
            ok[j]  = f2bf(xxf[j] + d * mk[j]);
            ov[j]  = f2bf(xxf[j] + d * mv[j]);
            orr[j] = f2bf(xxf[j] + d * mr[j]);
        }
        *(uint4*)(xk + e) = *(const uint4*)ok;
        *(uint4*)(xv + e) = *(const uint4*)ov;
        *(uint4*)(xr + e) = *(const uint4*)orr;
    } else {
        int wb = bid - 4096;                 // 0..2047
        int m = wb >> 9;                     // matrix 0..3
        const float* src; u16* dst;
        switch (m) {
            case 0: src = w0; dst = o0; break;
            case 1: src = w1; dst = o1; break;
            case 2: src = w2; dst = o2; break;
            default: src = w3; dst = o3; break;
        }
        int i = (((wb & 511) << 8) + threadIdx.x) << 3;
        float a[8];
        *(float4*)(a)     = *(const float4*)(src + i);
        *(float4*)(a + 4) = *(const float4*)(src + i + 4);
        u16 o[8];
#pragma unroll
        for (int j = 0; j < 8; j++) o[j] = f2bf(a[j]);
        *(uint4*)(dst + i) = *(const uint4*)o;
    }
}

// ---- GEMM body: C[8192,1024] = A[8192,1024] * Bw[1024,1024]^T (bf16 MFMA) -----
// 128x128 tile, BK=64 (two 32-wide LDS stage pairs per barrier-pair).
// FRAGMENT-MAJOR LDS layout: stage buffer = 8 fragments x 1KB; fragment
// f = i*2 + half holds rows half*64 + i*16 + (0..15), k-chunks 0..3, stored in
// exactly the order reader lanes consume (addr = f*1KB + lane*16B -> stride-1,
// bank-conflict-free). Writer lanes re-aim global source to match:
// lane j of wave w loads row (w&1)*64 + (w>>1)*16 + (j&15), k-chunk j>>4.
template <int BF16OUT>
__device__ __forceinline__ void gemm_body(
    const u16* __restrict__ A, const u16* __restrict__ Bw, void* __restrict__ Cout,
    u16* As0, u16* Bs0, u16* As1, u16* Bs1, int bm, int bn)
{
    const int K = Cdim, N = Cdim;
    const int tid = threadIdx.x;
    const int lane = tid & 63, wave = tid >> 6;
    const int wm = (wave & 1) << 6, wn = (wave >> 1) << 6;
    const int fr = lane & 15, quad = lane >> 4;

    // staging source: fragment-major (see comment above)
    const int srow = ((wave & 1) << 6) + ((wave >> 1) << 4) + fr;
    const int skc = quad << 3;
    const u16* ga = A + (size_t)(bm * 128 + srow) * K + skc;
    const u16* gb = Bw + (size_t)(bn * 128 + srow) * K + skc;
    u16* la0 = As0 + (wave << 9);   // fragment w (1KB); HW adds lane*16B
    u16* lb0 = Bs0 + (wave << 9);
    u16* la1 = As1 + (wave << 9);
    u16* lb1 = Bs1 + (wave << 9);
    const size_t gstep = (size_t)32 * K;   // fragment w+4 = rows +32

    f32x4 acc[4][4];
#pragma unroll
    for (int i = 0; i < 4; i++)
#pragma unroll
        for (int j = 0; j < 4; j++)
            acc[i][j] = (f32x4){0.f, 0.f, 0.f, 0.f};

    const int hA = wave & 1, hB = wave >> 1;

    for (int k0 = 0; k0 < K; k0 += 64) {
        __syncthreads();
        gload16(ga, la0);
        gload16(ga + gstep, la0 + 2048);
        gload16(gb, lb0);
        gload16(gb + gstep, lb0 + 2048);
        gload16(ga + 32, la1);
        gload16(ga + 32 + gstep, la1 + 2048);
        gload16(gb + 32, lb1);
        gload16(gb + 32 + gstep, lb1 + 2048);
        ga += 64; gb += 64;
        __syncthreads();
#pragma unroll
        for (int h = 0; h < 2; h++) {
            const u16* Ah = h ? As1 : As0;
            const u16* Bh = h ? Bs1 : Bs0;
            bf16x8 af[4], bfr[4];
#pragma unroll
            for (int i = 0; i < 4; i++) {
                af[i]  = *(const bf16x8*)(Ah + (((i << 1) + hA) << 9) + (lane << 3));
                bfr[i] = *(const bf16x8*)(Bh + (((i << 1) + hB) << 9) + (lane << 3));
            }
#pragma unroll
            for (int i = 0; i < 4; i++)
#pragma unroll
                for (int j = 0; j < 4; j++)
                    acc[i][j] = __builtin_amdgcn_mfma_f32_16x16x32_bf16(
                        af[i], bfr[j], acc[i][j], 0, 0, 0);
        }
    }

    // C/D layout: row = quad*4 + reg, col = lane&15  [m89-verified]
    const int gr0 = bm * 128 + wm + quad * 4;
    const int gc0 = bn * 128 + wn + fr;
#pragma unroll
    for (int i = 0; i < 4; i++)
#pragma unroll
        for (int j = 0; j < 4; j++)
#pragma unroll
            for (int r = 0; r < 4; r++) {
                int gr = gr0 + i * 16 + r;
                int gc = gc0 + j * 16;
                float val = acc[i][j][r];
                if (BF16OUT)
                    ((u16*)Cout)[(size_t)gr * N + gc] = f2bf(val);
                else
                    ((float*)Cout)[(size_t)gr * N + gc] = val;
            }
}

// grouped GEMM for k/v/r (blockIdx.z selects operand set), bf16 out
// XCD swizzle: bm = x&63 -> XCD = x%8 = bm%8, so all 8 bn-blocks sharing an
// A row-block co-reside on one XCD (per-XCD L2 working set fits).
__global__ __launch_bounds__(256) void gemm3_kernel(
    const u16* __restrict__ xk, const u16* __restrict__ xv, const u16* __restrict__ xr,
    const u16* __restrict__ wk, const u16* __restrict__ wv, const u16* __restrict__ wr,
    u16* __restrict__ ck, u16* __restrict__ cv, u16* __restrict__ cr)
{
    __shared__ u16 As0[128 * 32], Bs0[128 * 32], As1[128 * 32], Bs1[128 * 32];
    const u16* A; const u16* Bw; u16* Cout;
    switch (blockIdx.z) {
        case 0:  A = xk; Bw = wk; Cout = ck; break;
        case 1:  A = xv; Bw = wv; Cout = cv; break;
        default: A = xr; Bw = wr; Cout = cr; break;
    }
    int bx = blockIdx.x;
    gemm_body<1>(A, Bw, (void*)Cout, As0, Bs0, As1, Bs1, bx & 63, bx >> 6);
}

// final GEMM, f32 out
__global__ __launch_bounds__(256) void gemmo_kernel(
    const u16* __restrict__ A, const u16* __restrict__ Bw, float* __restrict__ Cout)
{
    __shared__ u16 As0[128 * 32], Bs0[128 * 32], As1[128 * 32], Bs1[128 * 32];
    int bx = blockIdx.x;
    gemm_body<0>(A, Bw, (void*)Cout, As0, Bs0, As1, Bs1, bx & 63, bx >> 6);
}

// ---- WKV scan + sigmoid(r) gate; 2 independent streams per thread (ILP) -------
#define WT 8

#define LOADCHUNK(KA, VA, RA, BASE, T0)                                  \
    _Pragma("unroll")                                                    \
    for (int s = 0; s < WT; s++) {                                       \
        size_t idx = (BASE) + (size_t)((T0) + s) * Cdim;                 \
        KA[s] = kb[idx]; VA[s] = vb[idx]; RA[s] = rb[idx];               \
    }

#define COMPCHUNK(KA, VA, RA, BASE, T0, p, q, o)                         \
    _Pragma("unroll")                                                    \
    for (int s = 0; s < WT; s++) {                                       \
        float kt = bf2f(KA[s]);                                          \
        float vt = bf2f(VA[s]);                                          \
        float rt = bf2f(RA[s]);                                          \
        float uk = u + kt;                                               \
        float no = fmaxf(o, uk);                                         \
        float Ae = __expf(o - no);                                       \
        float Bc = __expf(uk - no);                                      \
        float num = Ae * p + Bc * vt;                                    \
        float den = Ae * q + Bc;                                         \
        float y = num * __builtin_amdgcn_rcpf(den);                      \
        float sr = __builtin_amdgcn_rcpf(1.f + __expf(-rt));             \
        rwkv[(BASE) + (size_t)((T0) + s) * Cdim] = f2bf(y * sr);         \
        float wo = w + o;                                                \
        float no2 = fmaxf(wo, kt);                                       \
        float A2 = __expf(wo - no2);                                     \
        float B2 = __expf(kt - no2);                                     \
        p = A2 * p + B2 * vt;                                            \
        q = A2 * q + B2;                                                 \
        o = no2;                                                         \
    }

__global__ __launch_bounds__(64) void wkv_kernel(
    const u16* __restrict__ kb, const u16* __restrict__ vb,
    const u16* __restrict__ rb, const float* __restrict__ td,
    const float* __restrict__ tfirst, u16* __restrict__ rwkv)
{
    int lane = threadIdx.x;
    int blk = blockIdx.x;            // 256 blocks
    int b0 = blk >> 4;               // batches b0 and b0+16
    int c = ((blk & 15) << 6) + lane;
    float w = -__expf(td[c]);
    float u = tfirst[c];
    const size_t base0 = (size_t)b0 * Tdim * Cdim + c;
    const size_t base1 = (size_t)(b0 + 16) * Tdim * Cdim + c;

    u32 k0A[WT], v0A[WT], r0A[WT], k0B[WT], v0B[WT], r0B[WT];
    u32 k1A[WT], v1A[WT], r1A[WT], k1B[WT], v1B[WT], r1B[WT];
    float p0 = 0.f, q0 = 0.f, o0 = -1e38f;
    float p1 = 0.f, q1 = 0.f, o1 = -1e38f;

    LOADCHUNK(k0A, v0A, r0A, base0, 0)
    LOADCHUNK(k1A, v1A, r1A, base1, 0)
    for (int t0 = 0; t0 < Tdim; t0 += 2 * WT) {
        LOADCHUNK(k0B, v0B, r0B, base0, t0 + WT)
        LOADCHUNK(k1B, v1B, r1B, base1, t0 + WT)
        COMPCHUNK(k0A, v0A, r0A, base0, t0, p0, q0, o0)
        COMPCHUNK(k1A, v1A, r1A, base1, t0, p1, q1, o1)
        if (t0 + 2 * WT < Tdim) {
            LOADCHUNK(k0A, v0A, r0A, base0, t0 + 2 * WT)
            LOADCHUNK(k1A, v1A, r1A, base1, t0 + 2 * WT)
        }
        COMPCHUNK(k0B, v0B, r0B, base0, t0 + WT, p0, q0, o0)
        COMPCHUNK(k1B, v1B, r1B, base1, t0 + WT, p1, q1, o1)
    }
}

extern "C" void kernel_launch(void* const* d_in, const int* in_sizes, int n_in,
                              void* d_out, int out_size, void* d_ws, size_t ws_size,
                              hipStream_t stream) {
    (void)in_sizes; (void)n_in; (void)out_size; (void)ws_size;
    const float* x   = (const float*)d_in[0];
    const float* td  = (const float*)d_in[1];
    const float* tfi = (const float*)d_in[2];
    const float* tmk = (const float*)d_in[3];
    const float* tmv = (const float*)d_in[4];
    const float* tmr = (const float*)d_in[5];
    const float* Wk  = (const float*)d_in[6];
    const float* Wv  = (const float*)d_in[7];
    const float* Wr  = (const float*)d_in[8];
    const float* Wo  = (const float*)d_in[9];

    char* ws = (char*)d_ws;
    const size_t MiB = (size_t)1 << 20;
    u16* xk    = (u16*)(ws);             // [0,16)
    u16* xv    = (u16*)(ws + 16 * MiB);  // [16,32)
    u16* xr    = (u16*)(ws + 32 * MiB);  // [32,48)
    u16* wkb   = (u16*)(ws + 48 * MiB);  // [48,50)
    u16* wvb   = (u16*)(ws + 50 * MiB);  // [50,52)
    u16* wrb   = (u16*)(ws + 52 * MiB);  // [52,54)
    u16* wob   = (u16*)(ws + 54 * MiB);  // [54,56)
    u16* kb    = (u16*)(ws + 56 * MiB);  // [56,72)
    u16* vb    = (u16*)(ws + 72 * MiB);  // [72,88)
    u16* rb    = (u16*)(ws + 88 * MiB);  // [88,104) — no alias: gemm3 z's run concurrently
    u16* rwkvb = (u16*)(ws);             // [0,16) — overlaps xk (dead after gemm3)

    prep_fused<<<6144, 256, 0, stream>>>(x, tmk, tmv, tmr, xk, xv, xr,
                                         Wk, Wv, Wr, Wo, wkb, wvb, wrb, wob);

    gemm3_kernel<<<dim3(512, 1, 3), 256, 0, stream>>>(xk, xv, xr, wkb, wvb, wrb,
                                                      kb, vb, rb);

    wkv_kernel<<<256, 64, 0, stream>>>(kb, vb, rb, td, tfi, rwkvb);

    gemmo_kernel<<<512, 256, 0, stream>>>(rwkvb, wob, (float*)d_out);
}

// Round 6
// 229.239 us; speedup vs baseline: 1.3140x; 1.3140x over previous
//
#include <hip/hip_runtime.h>

#define Bdim 32
#define Tdim 256
#define Cdim 1024
#define Mrows (Bdim * Tdim) /* 8192 */

typedef unsigned short u16;
typedef unsigned int u32;
typedef __bf16 bf16x8 __attribute__((ext_vector_type(8)));
typedef float f32x4 __attribute__((ext_vector_type(4)));

__device__ __forceinline__ float bf2f(u32 u) {
    union { u32 i; float f; } v; v.i = u << 16; return v.f;
}
__device__ __forceinline__ u16 f2bf(float f) {
    union { float f; u32 i; } v; v.f = f;
    u32 u = v.i;
    return (u16)((u + 0x7fffu + ((u >> 16) & 1u)) >> 16);  // RNE
}

__device__ __forceinline__ void gload16(const u16* g, u16* l) {
    __builtin_amdgcn_global_load_lds(
        (__attribute__((address_space(1))) const void*)g,
        (__attribute__((address_space(3))) void*)l, 16, 0, 0);
}

// ---- fused prep (x mixing -> bf16) + weight convert ---------------------------
__global__ __launch_bounds__(256) void prep_fused(
    const float* __restrict__ x, const float* __restrict__ tmk,
    const float* __restrict__ tmv, const float* __restrict__ tmr,
    u16* __restrict__ xk, u16* __restrict__ xv, u16* __restrict__ xr,
    const float* __restrict__ w0, const float* __restrict__ w1,
    const float* __restrict__ w2, const float* __restrict__ w3,
    u16* __restrict__ o0, u16* __restrict__ o1,
    u16* __restrict__ o2, u16* __restrict__ o3)
{
    int bid = blockIdx.x;
    if (bid < 4096) {
        int tid = bid * 256 + threadIdx.x;
        int e = tid << 3;
        int c = e & (Cdim - 1);
        int t = (e >> 10) & (Tdim - 1);
        float xf[8], xxf[8], mk[8], mv[8], mr[8];
        *(float4*)(xf)     = *(const float4*)(x + e);
        *(float4*)(xf + 4) = *(const float4*)(x + e + 4);
        if (t != 0) {
            *(float4*)(xxf)     = *(const float4*)(x + e - Cdim);
            *(float4*)(xxf + 4) = *(const float4*)(x + e - Cdim + 4);
        } else {
#pragma unroll
            for (int j = 0; j < 8; j++) xxf[j] = 0.f;
        }
        *(float4*)(mk)     = *(const float4*)(tmk + c);
        *(float4*)(mk + 4) = *(const float4*)(tmk + c + 4);
        *(float4*)(mv)     = *(const float4*)(tmv + c);
        *(float4*)(mv + 4) = *(const float4*)(tmv + c + 4);
        *(float4*)(mr)     = *(const float4*)(tmr + c);
        *(float4*)(mr + 4) = *(const float4*)(tmr + c + 4);
        u16 ok[8], ov[8], orr[8];
#pragma unroll
        for (int j = 0; j < 8; j++) {
            float d = xf[j] - xxf[j];
            ok[j]  = f2bf(xxf[j] + d * mk[j]);
            ov[j]  = f2bf(xxf[j] + d * mv[j]);
            orr[j] = f2bf(xxf[j] + d * mr[j]);
        }
        *(uint4*)(xk + e) = *(const uint4*)ok;
        *(uint4*)(xv + e) = *(const uint4*)ov;
        *(uint4*)(xr + e) = *(const uint4*)orr;
    } else {
        int wb = bid - 4096;                 // 0..2047
        int m = wb >> 9;                     // matrix 0..3
        const float* src; u16* dst;
        switch (m) {
            case 0: src = w0; dst = o0; break;
            case 1: src = w1; dst = o1; break;
            case 2: src = w2; dst = o2; break;
            default: src = w3; dst = o3; break;
        }
        int i = (((wb & 511) << 8) + threadIdx.x) << 3;
        float a[8];
        *(float4*)(a)     = *(const float4*)(src + i);
        *(float4*)(a + 4) = *(const float4*)(src + i + 4);
        u16 o[8];
#pragma unroll
        for (int j = 0; j < 8; j++) o[j] = f2bf(a[j]);
        *(uint4*)(dst + i) = *(const uint4*)o;
    }
}

// ---- GEMM body: C[8192,1024] = A[8192,1024] * Bw[1024,1024]^T (bf16 MFMA) -----
// 128x128 tile, BK=64 (two 32-wide LDS stage pairs per barrier-pair).
// R4 staging layout (coalesced 64B row-groups) + 2-bit chunk XOR swizzle:
// writer lane j fetches k-chunk (j&3)^((j>>2)&3) of its row — same 64B global
// segment (coalescing unchanged), but LDS slot (row,pos) now holds chunk
// pos^(row&3). Reader reads pos = quad^(fr&3): per-8-lane phase bank spread
// becomes 2-way (free, m136) instead of 8-way.
template <int BF16OUT>
__device__ __forceinline__ void gemm_body(
    const u16* __restrict__ A, const u16* __restrict__ Bw, void* __restrict__ Cout,
    u16* As0, u16* Bs0, u16* As1, u16* Bs1, int bm, int bn)
{
    const int K = Cdim, N = Cdim;
    const int tid = threadIdx.x;
    const int lane = tid & 63, wave = tid >> 6;
    const int wm = (wave & 1) << 6, wn = (wave >> 1) << 6;
    const int fr = lane & 15, quad = lane >> 4;

    const int srow = tid >> 2;
    const int skc = (((tid & 3) ^ ((tid >> 2) & 3)) << 3);  // XOR-swizzled chunk
    const u16* ga = A + (size_t)(bm * 128 + srow) * K + skc;
    const u16* gb = Bw + (size_t)(bn * 128 + srow) * K + skc;
    u16* la0 = As0 + (wave << 9);   // wave-uniform LDS base; HW adds lane*16B
    u16* lb0 = Bs0 + (wave << 9);
    u16* la1 = As1 + (wave << 9);
    u16* lb1 = Bs1 + (wave << 9);
    const size_t gstep = (size_t)64 * K;

    f32x4 acc[4][4];
#pragma unroll
    for (int i = 0; i < 4; i++)
#pragma unroll
        for (int j = 0; j < 4; j++)
            acc[i][j] = (f32x4){0.f, 0.f, 0.f, 0.f};

    const int rq = ((quad ^ (fr & 3)) << 3);  // reader chunk offset (u16 units)

    for (int k0 = 0; k0 < K; k0 += 64) {
        __syncthreads();
        gload16(ga, la0);
        gload16(ga + gstep, la0 + 2048);
        gload16(gb, lb0);
        gload16(gb + gstep, lb0 + 2048);
        gload16(ga + 32, la1);
        gload16(ga + 32 + gstep, la1 + 2048);
        gload16(gb + 32, lb1);
        gload16(gb + 32 + gstep, lb1 + 2048);
        ga += 64; gb += 64;
        __syncthreads();
#pragma unroll
        for (int h = 0; h < 2; h++) {
            const u16* Ah = h ? As1 : As0;
            const u16* Bh = h ? Bs1 : Bs0;
            bf16x8 af[4], bfr[4];
#pragma unroll
            for (int i = 0; i < 4; i++) {
                af[i]  = *(const bf16x8*)(Ah + (wm + i * 16 + fr) * 32 + rq);
                bfr[i] = *(const bf16x8*)(Bh + (wn + i * 16 + fr) * 32 + rq);
            }
#pragma unroll
            for (int i = 0; i < 4; i++)
#pragma unroll
                for (int j = 0; j < 4; j++)
                    acc[i][j] = __builtin_amdgcn_mfma_f32_16x16x32_bf16(
                        af[i], bfr[j], acc[i][j], 0, 0, 0);
        }
    }

    // C/D layout: row = quad*4 + reg, col = lane&15  [m89-verified]
    const int gr0 = bm * 128 + wm + quad * 4;
    const int gc0 = bn * 128 + wn + fr;
#pragma unroll
    for (int i = 0; i < 4; i++)
#pragma unroll
        for (int j = 0; j < 4; j++)
#pragma unroll
            for (int r = 0; r < 4; r++) {
                int gr = gr0 + i * 16 + r;
                int gc = gc0 + j * 16;
                float val = acc[i][j][r];
                if (BF16OUT)
                    ((u16*)Cout)[(size_t)gr * N + gc] = f2bf(val);
                else
                    ((float*)Cout)[(size_t)gr * N + gc] = val;
            }
}

// grouped GEMM for k/v/r (blockIdx.z selects operand set), bf16 out
// XCD swizzle: bm = x&63 -> XCD = x%8 = bm%8, so all 8 bn-blocks sharing an
// A row-block co-reside on one XCD (per-XCD L2 working set fits).
__global__ __launch_bounds__(256) void gemm3_kernel(
    const u16* __restrict__ xk, const u16* __restrict__ xv, const u16* __restrict__ xr,
    const u16* __restrict__ wk, const u16* __restrict__ wv, const u16* __restrict__ wr,
    u16* __restrict__ ck, u16* __restrict__ cv, u16* __restrict__ cr)
{
    __shared__ u16 As0[128 * 32], Bs0[128 * 32], As1[128 * 32], Bs1[128 * 32];
    const u16* A; const u16* Bw; u16* Cout;
    switch (blockIdx.z) {
        case 0:  A = xk; Bw = wk; Cout = ck; break;
        case 1:  A = xv; Bw = wv; Cout = cv; break;
        default: A = xr; Bw = wr; Cout = cr; break;
    }
    int bx = blockIdx.x;
    gemm_body<1>(A, Bw, (void*)Cout, As0, Bs0, As1, Bs1, bx & 63, bx >> 6);
}

// final GEMM, f32 out
__global__ __launch_bounds__(256) void gemmo_kernel(
    const u16* __restrict__ A, const u16* __restrict__ Bw, float* __restrict__ Cout)
{
    __shared__ u16 As0[128 * 32], Bs0[128 * 32], As1[128 * 32], Bs1[128 * 32];
    int bx = blockIdx.x;
    gemm_body<0>(A, Bw, (void*)Cout, As0, Bs0, As1, Bs1, bx & 63, bx >> 6);
}

// ---- WKV scan + sigmoid(r) gate; register double-buffered prefetch ------------
#define WTC 16

#define LOADCHUNK(KA, VA, RA, T0)                                        \
    _Pragma("unroll")                                                    \
    for (int s = 0; s < WTC; s++) {                                      \
        size_t idx = base + (size_t)((T0) + s) * Cdim;                   \
        KA[s] = kb[idx]; VA[s] = vb[idx]; RA[s] = rb[idx];               \
    }

#define COMPCHUNK(KA, VA, RA, T0)                                        \
    _Pragma("unroll")                                                    \
    for (int s = 0; s < WTC; s++) {                                      \
        float kt = bf2f(KA[s]);                                          \
        float vt = bf2f(VA[s]);                                          \
        float rt = bf2f(RA[s]);                                          \
        float uk = u + kt;                                               \
        float no = fmaxf(o, uk);                                         \
        float Ae = __expf(o - no);                                       \
        float Bc = __expf(uk - no);                                      \
        float num = Ae * p + Bc * vt;                                    \
        float den = Ae * q + Bc;                                         \
        float y = num * __builtin_amdgcn_rcpf(den);                      \
        float sr = __builtin_amdgcn_rcpf(1.f + __expf(-rt));             \
        rwkv[base + (size_t)((T0) + s) * Cdim] = f2bf(y * sr);           \
        float wo = w + o;                                                \
        float no2 = fmaxf(wo, kt);                                       \
        float A2 = __expf(wo - no2);                                     \
        float B2 = __expf(kt - no2);                                     \
        p = A2 * p + B2 * vt;                                            \
        q = A2 * q + B2;                                                 \
        o = no2;                                                         \
    }

__global__ __launch_bounds__(64) void wkv_kernel(
    const u16* __restrict__ kb, const u16* __restrict__ vb,
    const u16* __restrict__ rb, const float* __restrict__ td,
    const float* __restrict__ tfirst, u16* __restrict__ rwkv)
{
    int lane = threadIdx.x;
    int blk = blockIdx.x;            // 512 blocks
    int b = blk >> 4;
    int c = ((blk & 15) << 6) + lane;
    float w = -__expf(td[c]);
    float u = tfirst[c];
    const size_t base = (size_t)b * Tdim * Cdim + c;

    u32 kA[WTC], vA[WTC], rA[WTC];
    u32 kB[WTC], vB[WTC], rB[WTC];
    float p = 0.f, q = 0.f, o = -1e38f;

    LOADCHUNK(kA, vA, rA, 0)
    for (int t0 = 0; t0 < Tdim; t0 += 2 * WTC) {
        LOADCHUNK(kB, vB, rB, t0 + WTC)
        COMPCHUNK(kA, vA, rA, t0)
        if (t0 + 2 * WTC < Tdim) {
            LOADCHUNK(kA, vA, rA, t0 + 2 * WTC)
        }
        COMPCHUNK(kB, vB, rB, t0 + WTC)
    }
}

extern "C" void kernel_launch(void* const* d_in, const int* in_sizes, int n_in,
                              void* d_out, int out_size, void* d_ws, size_t ws_size,
                              hipStream_t stream) {
    (void)in_sizes; (void)n_in; (void)out_size; (void)ws_size;
    const float* x   = (const float*)d_in[0];
    const float* td  = (const float*)d_in[1];
    const float* tfi = (const float*)d_in[2];
    const float* tmk = (const float*)d_in[3];
    const float* tmv = (const float*)d_in[4];
    const float* tmr = (const float*)d_in[5];
    const float* Wk  = (const float*)d_in[6];
    const float* Wv  = (const float*)d_in[7];
    const float* Wr  = (const float*)d_in[8];
    const float* Wo  = (const float*)d_in[9];

    char* ws = (char*)d_ws;
    const size_t MiB = (size_t)1 << 20;
    u16* xk    = (u16*)(ws);             // [0,16)
    u16* xv    = (u16*)(ws + 16 * MiB);  // [16,32)
    u16* xr    = (u16*)(ws + 32 * MiB);  // [32,48)
    u16* wkb   = (u16*)(ws + 48 * MiB);  // [48,50)
    u16* wvb   = (u16*)(ws + 50 * MiB);  // [50,52)
    u16* wrb   = (u16*)(ws + 52 * MiB);  // [52,54)
    u16* wob   = (u16*)(ws + 54 * MiB);  // [54,56)
    u16* kb    = (u16*)(ws + 56 * MiB);  // [56,72)
    u16* vb    = (u16*)(ws + 72 * MiB);  // [72,88)
    u16* rb    = (u16*)(ws + 88 * MiB);  // [88,104) — no alias: gemm3 z's run concurrently
    u16* rwkvb = (u16*)(ws);             // [0,16) — overlaps xk (dead after gemm3)

    prep_fused<<<6144, 256, 0, stream>>>(x, tmk, tmv, tmr, xk, xv, xr,
                                         Wk, Wv, Wr, Wo, wkb, wvb, wrb, wob);

    gemm3_kernel<<<dim3(512, 1, 3), 256, 0, stream>>>(xk, xv, xr, wkb, wvb, wrb,
                                                      kb, vb, rb);

    wkv_kernel<<<512, 64, 0, stream>>>(kb, vb, rb, td, tfi, rwkvb);

    gemmo_kernel<<<512, 256, 0, stream>>>(rwkvb, wob, (float*)d_out);
}

// Round 7
// 226.081 us; speedup vs baseline: 1.3324x; 1.0140x over previous
//
#include <hip/hip_runtime.h>

#define Bdim 32
#define Tdim 256
#define Cdim 1024
#define Mrows (Bdim * Tdim) /* 8192 */

typedef unsigned short u16;
typedef unsigned int u32;
typedef __bf16 bf16x8 __attribute__((ext_vector_type(8)));
typedef float f32x4 __attribute__((ext_vector_type(4)));

__device__ __forceinline__ float bf2f(u32 u) {
    union { u32 i; float f; } v; v.i = u << 16; return v.f;
}
__device__ __forceinline__ u16 f2bf(float f) {
    union { float f; u32 i; } v; v.f = f;
    u32 u = v.i;
    return (u16)((u + 0x7fffu + ((u >> 16) & 1u)) >> 16);  // RNE
}

__device__ __forceinline__ void gload16(const u16* g, u16* l) {
    __builtin_amdgcn_global_load_lds(
        (__attribute__((address_space(1))) const void*)g,
        (__attribute__((address_space(3))) void*)l, 16, 0, 0);
}

// ---- fused prep (x mixing -> bf16) + weight convert ---------------------------
__global__ __launch_bounds__(256) void prep_fused(
    const float* __restrict__ x, const float* __restrict__ tmk,
    const float* __restrict__ tmv, const float* __restrict__ tmr,
    u16* __restrict__ xk, u16* __restrict__ xv, u16* __restrict__ xr,
    const float* __restrict__ w0, const float* __restrict__ w1,
    const float* __restrict__ w2, const float* __restrict__ w3,
    u16* __restrict__ o0, u16* __restrict__ o1,
    u16* __restrict__ o2, u16* __restrict__ o3)
{
    int bid = blockIdx.x;
    if (bid < 4096) {
        int tid = bid * 256 + threadIdx.x;
        int e = tid << 3;
        int c = e & (Cdim - 1);
        int t = (e >> 10) & (Tdim - 1);
        float xf[8], xxf[8], mk[8], mv[8], mr[8];
        *(float4*)(xf)     = *(const float4*)(x + e);
        *(float4*)(xf + 4) = *(const float4*)(x + e + 4);
        if (t != 0) {
            *(float4*)(xxf)     = *(const float4*)(x + e - Cdim);
            *(float4*)(xxf + 4) = *(const float4*)(x + e - Cdim + 4);
        } else {
#pragma unroll
            for (int j = 0; j < 8; j++) xxf[j] = 0.f;
        }
        *(float4*)(mk)     = *(const float4*)(tmk + c);
        *(float4*)(mk + 4) = *(const float4*)(tmk + c + 4);
        *(float4*)(mv)     = *(const float4*)(tmv + c);
        *(float4*)(mv + 4) = *(const float4*)(tmv + c + 4);
        *(float4*)(mr)     = *(const float4*)(tmr + c);
        *(float4*)(mr + 4) = *(const float4*)(tmr + c + 4);
        u16 ok[8], ov[8], orr[8];
#pragma unroll
        for (int j = 0; j < 8; j++) {
            float d = xf[j] - xxf[j];
            ok[j]  = f2bf(xxf[j] + d * mk[j]);
            ov[j]  = f2bf(xxf[j] + d * mv[j]);
            orr[j] = f2bf(xxf[j] + d * mr[j]);
        }
        *(uint4*)(xk + e) = *(const uint4*)ok;
        *(uint4*)(xv + e) = *(const uint4*)ov;
        *(uint4*)(xr + e) = *(const uint4*)orr;
    } else {
        int wb = bid - 4096;                 // 0..2047
        int m = wb >> 9;                     // matrix 0..3
        const float* src; u16* dst;
        switch (m) {
            case 0: src = w0; dst = o0; break;
            case 1: src = w1; dst = o1; break;
            case 2: src = w2; dst = o2; break;
            default: src = w3; dst = o3; break;
        }
        int i = (((wb & 511) << 8) + threadIdx.x) << 3;
        float a[8];
        *(float4*)(a)     = *(const float4*)(src + i);
        *(float4*)(a + 4) = *(const float4*)(src + i + 4);
        u16 o[8];
#pragma unroll
        for (int j = 0; j < 8; j++) o[j] = f2bf(a[j]);
        *(uint4*)(dst + i) = *(const uint4*)o;
    }
}

// ---- GEMM body: C[8192,1024] = A[8192,1024] * Bw[1024,1024]^T (bf16 MFMA) -----
// 128x128 tile, BK=64 (two 32-wide LDS stage pairs per barrier-pair).
// ROTATION SWIZZLE (period-8 in row): LDS slot (row,pos) holds k-chunk
// (pos + ((row>>1)&3))&3. Writer thread t (row=t>>2,pos=t&3) fetches global
// chunk ((t&3)+((t>>3)&3))&3 — a permutation within the row's 64B segment,
// so global coalescing is identical to R4. Reader lane (fr,quad) reads
// pos=(quad-((fr>>1)&3))&3 -> per-8-lane phase, bank columns are a perfect
// permutation of 0..7 (conflict-free). [R6's fr&3 XOR had period 4 -> lanes
// fr,fr+4 collided; conflicts unchanged at 6.29M. This fixes that.]
template <int BF16OUT>
__device__ __forceinline__ void gemm_body(
    const u16* __restrict__ A, const u16* __restrict__ Bw, void* __restrict__ Cout,
    u16* As0, u16* Bs0, u16* As1, u16* Bs1, int bm, int bn)
{
    const int K = Cdim, N = Cdim;
    const int tid = threadIdx.x;
    const int lane = tid & 63, wave = tid >> 6;
    const int wm = (wave & 1) << 6, wn = (wave >> 1) << 6;
    const int fr = lane & 15, quad = lane >> 4;

    const int srow = tid >> 2;
    const int skc = ((((tid & 3) + ((tid >> 3) & 3)) & 3) << 3);  // rotated chunk
    const u16* ga = A + (size_t)(bm * 128 + srow) * K + skc;
    const u16* gb = Bw + (size_t)(bn * 128 + srow) * K + skc;
    u16* la0 = As0 + (wave << 9);   // wave-uniform LDS base; HW adds lane*16B
    u16* lb0 = Bs0 + (wave << 9);
    u16* la1 = As1 + (wave << 9);
    u16* lb1 = Bs1 + (wave << 9);
    const size_t gstep = (size_t)64 * K;

    f32x4 acc[4][4];
#pragma unroll
    for (int i = 0; i < 4; i++)
#pragma unroll
        for (int j = 0; j < 4; j++)
            acc[i][j] = (f32x4){0.f, 0.f, 0.f, 0.f};

    const int rq = (((quad - ((fr >> 1) & 3)) & 3) << 3);  // reader pos (u16 units)

    for (int k0 = 0; k0 < K; k0 += 64) {
        __syncthreads();
        gload16(ga, la0);
        gload16(ga + gstep, la0 + 2048);
        gload16(gb, lb0);
        gload16(gb + gstep, lb0 + 2048);
        gload16(ga + 32, la1);
        gload16(ga + 32 + gstep, la1 + 2048);
        gload16(gb + 32, lb1);
        gload16(gb + 32 + gstep, lb1 + 2048);
        ga += 64; gb += 64;
        __syncthreads();
#pragma unroll
        for (int h = 0; h < 2; h++) {
            const u16* Ah = h ? As1 : As0;
            const u16* Bh = h ? Bs1 : Bs0;
            bf16x8 af[4], bfr[4];
#pragma unroll
            for (int i = 0; i < 4; i++) {
                af[i]  = *(const bf16x8*)(Ah + (wm + i * 16 + fr) * 32 + rq);
                bfr[i] = *(const bf16x8*)(Bh + (wn + i * 16 + fr) * 32 + rq);
            }
#pragma unroll
            for (int i = 0; i < 4; i++)
#pragma unroll
                for (int j = 0; j < 4; j++)
                    acc[i][j] = __builtin_amdgcn_mfma_f32_16x16x32_bf16(
                        af[i], bfr[j], acc[i][j], 0, 0, 0);
        }
    }

    // C/D layout: row = quad*4 + reg, col = lane&15  [m89-verified]
    const int gr0 = bm * 128 + wm + quad * 4;
    const int gc0 = bn * 128 + wn + fr;
#pragma unroll
    for (int i = 0; i < 4; i++)
#pragma unroll
        for (int j = 0; j < 4; j++)
#pragma unroll
            for (int r = 0; r < 4; r++) {
                int gr = gr0 + i * 16 + r;
                int gc = gc0 + j * 16;
                float val = acc[i][j][r];
                if (BF16OUT)
                    ((u16*)Cout)[(size_t)gr * N + gc] = f2bf(val);
                else
                    ((float*)Cout)[(size_t)gr * N + gc] = val;
            }
}

// grouped GEMM for k/v/r (blockIdx.z selects operand set), bf16 out
// XCD swizzle: bm = x&63 -> XCD = x%8 = bm%8, so all 8 bn-blocks sharing an
// A row-block co-reside on one XCD (per-XCD L2 working set fits).
__global__ __launch_bounds__(256) void gemm3_kernel(
    const u16* __restrict__ xk, const u16* __restrict__ xv, const u16* __restrict__ xr,
    const u16* __restrict__ wk, const u16* __restrict__ wv, const u16* __restrict__ wr,
    u16* __restrict__ ck, u16* __restrict__ cv, u16* __restrict__ cr)
{
    __shared__ u16 As0[128 * 32], Bs0[128 * 32], As1[128 * 32], Bs1[128 * 32];
    const u16* A; const u16* Bw; u16* Cout;
    switch (blockIdx.z) {
        case 0:  A = xk; Bw = wk; Cout = ck; break;
        case 1:  A = xv; Bw = wv; Cout = cv; break;
        default: A = xr; Bw = wr; Cout = cr; break;
    }
    int bx = blockIdx.x;
    gemm_body<1>(A, Bw, (void*)Cout, As0, Bs0, As1, Bs1, bx & 63, bx >> 6);
}

// final GEMM, f32 out
__global__ __launch_bounds__(256) void gemmo_kernel(
    const u16* __restrict__ A, const u16* __restrict__ Bw, float* __restrict__ Cout)
{
    __shared__ u16 As0[128 * 32], Bs0[128 * 32], As1[128 * 32], Bs1[128 * 32];
    int bx = blockIdx.x;
    gemm_body<0>(A, Bw, (void*)Cout, As0, Bs0, As1, Bs1, bx & 63, bx >> 6);
}

// ---- WKV scan + sigmoid(r) gate; register double-buffered prefetch ------------
#define WTC 16

#define LOADCHUNK(KA, VA, RA, T0)                                        \
    _Pragma("unroll")                                                    \
    for (int s = 0; s < WTC; s++) {                                      \
        size_t idx = base + (size_t)((T0) + s) * Cdim;                   \
        KA[s] = kb[idx]; VA[s] = vb[idx]; RA[s] = rb[idx];               \
    }

#define COMPCHUNK(KA, VA, RA, T0)                                        \
    _Pragma("unroll")                                                    \
    for (int s = 0; s < WTC; s++) {                                      \
        float kt = bf2f(KA[s]);                                          \
        float vt = bf2f(VA[s]);                                          \
        float rt = bf2f(RA[s]);                                          \
        float uk = u + kt;                                               \
        float no = fmaxf(o, uk);                                         \
        float Ae = __expf(o - no);                                       \
        float Bc = __expf(uk - no);                                      \
        float num = Ae * p + Bc * vt;                                    \
        float den = Ae * q + Bc;                                         \
        float y = num * __builtin_amdgcn_rcpf(den);                      \
        float sr = __builtin_amdgcn_rcpf(1.f + __expf(-rt));             \
        rwkv[base + (size_t)((T0) + s) * Cdim] = f2bf(y * sr);           \
        float wo = w + o;                                                \
        float no2 = fmaxf(wo, kt);                                       \
        float A2 = __expf(wo - no2);                                     \
        float B2 = __expf(kt - no2);                                     \
        p = A2 * p + B2 * vt;                                            \
        q = A2 * q + B2;                                                 \
        o = no2;                                                         \
    }

__global__ __launch_bounds__(64) void wkv_kernel(
    const u16* __restrict__ kb, const u16* __restrict__ vb,
    const u16* __restrict__ rb, const float* __restrict__ td,
    const float* __restrict__ tfirst, u16* __restrict__ rwkv)
{
    int lane = threadIdx.x;
    int blk = blockIdx.x;            // 512 blocks
    int b = blk >> 4;
    int c = ((blk & 15) << 6) + lane;
    float w = -__expf(td[c]);
    float u = tfirst[c];
    const size_t base = (size_t)b * Tdim * Cdim + c;

    u32 kA[WTC], vA[WTC], rA[WTC];
    u32 kB[WTC], vB[WTC], rB[WTC];
    float p = 0.f, q = 0.f, o = -1e38f;

    LOADCHUNK(kA, vA, rA, 0)
    for (int t0 = 0; t0 < Tdim; t0 += 2 * WTC) {
        LOADCHUNK(kB, vB, rB, t0 + WTC)
        COMPCHUNK(kA, vA, rA, t0)
        if (t0 + 2 * WTC < Tdim) {
            LOADCHUNK(kA, vA, rA, t0 + 2 * WTC)
        }
        COMPCHUNK(kB, vB, rB, t0 + WTC)
    }
}

extern "C" void kernel_launch(void* const* d_in, const int* in_sizes, int n_in,
                              void* d_out, int out_size, void* d_ws, size_t ws_size,
                              hipStream_t stream) {
    (void)in_sizes; (void)n_in; (void)out_size; (void)ws_size;
    const float* x   = (const float*)d_in[0];
    const float* td  = (const float*)d_in[1];
    const float* tfi = (const float*)d_in[2];
    const float* tmk = (const float*)d_in[3];
    const float* tmv = (const float*)d_in[4];
    const float* tmr = (const float*)d_in[5];
    const float* Wk  = (const float*)d_in[6];
    const float* Wv  = (const float*)d_in[7];
    const float* Wr  = (const float*)d_in[8];
    const float* Wo  = (const float*)d_in[9];

    char* ws = (char*)d_ws;
    const size_t MiB = (size_t)1 << 20;
    u16* xk    = (u16*)(ws);             // [0,16)
    u16* xv    = (u16*)(ws + 16 * MiB);  // [16,32)
    u16* xr    = (u16*)(ws + 32 * MiB);  // [32,48)
    u16* wkb   = (u16*)(ws + 48 * MiB);  // [48,50)
    u16* wvb   = (u16*)(ws + 50 * MiB);  // [50,52)
    u16* wrb   = (u16*)(ws + 52 * MiB);  // [52,54)
    u16* wob   = (u16*)(ws + 54 * MiB);  // [54,56)
    u16* kb    = (u16*)(ws + 56 * MiB);  // [56,72)
    u16* vb    = (u16*)(ws + 72 * MiB);  // [72,88)
    u16* rb    = (u16*)(ws + 88 * MiB);  // [88,104) — no alias: gemm3 z's run concurrently
    u16* rwkvb = (u16*)(ws);             // [0,16) — overlaps xk (dead after gemm3)

    prep_fused<<<6144, 256, 0, stream>>>(x, tmk, tmv, tmr, xk, xv, xr,
                                         Wk, Wv, Wr, Wo, wkb, wvb, wrb, wob);

    gemm3_kernel<<<dim3(512, 1, 3), 256, 0, stream>>>(xk, xv, xr, wkb, wvb, wrb,
                                                      kb, vb, rb);

    wkv_kernel<<<512, 64, 0, stream>>>(kb, vb, rb, td, tfi, rwkvb);

    gemmo_kernel<<<512, 256, 0, stream>>>(rwkvb, wob, (float*)d_out);
}